// Round 17
// baseline (141.654 us; speedup 1.0000x reference)
//
#include <hip/hip_runtime.h>
#include <hip/hip_bf16.h>
#include <stdint.h>

typedef __bf16 bf16x8  __attribute__((ext_vector_type(8)));
typedef __bf16 bf16x4  __attribute__((ext_vector_type(4)));
typedef __bf16 bf16x16 __attribute__((ext_vector_type(16)));
typedef float  f32x4   __attribute__((ext_vector_type(4)));
typedef float  f32x16  __attribute__((ext_vector_type(16)));
typedef uint32_t u32;

#define MFMA16(a, b, c) __builtin_amdgcn_mfma_f32_16x16x32_bf16((a), (b), (c), 0, 0, 0)
#define MFMA32(a, b, c) __builtin_amdgcn_mfma_f32_32x32x16_bf16((a), (b), (c), 0, 0, 0)

#if __has_builtin(__builtin_amdgcn_exp2f)
#define EXP2F(x) __builtin_amdgcn_exp2f(x)
#else
#define EXP2F(x) exp2f(x)
#endif

constexpr int CH = 160, CW = 160, CC = 192, CHEADS = 6, CD = 32;
constexpr int CNQ = 256, CNKV = 576, CPH = 168;
constexpr float LOG2E = 1.44269504088896340736f;
constexpr float QSCALE_L2E = 0.17677669529663687f * 1.44269504088896340736f;

// ---------------------------------------------------------------------------
// Merged prep kernel (R9-proven).
// ---------------------------------------------------------------------------
__global__ __launch_bounds__(256)
void prep_k(const int* __restrict__ rpi, const float* __restrict__ tab,
            const float* __restrict__ q_w, const float* __restrict__ g_w,
            const float* __restrict__ kv_w, const float* __restrict__ p_w,
            const float* __restrict__ q_b, const float* __restrict__ g_b,
            const float* __restrict__ kv_b, const float* __restrict__ p_b,
            __bf16* __restrict__ BTh, u32* __restrict__ mt,
            __bf16* __restrict__ Wt, __bf16* __restrict__ Wp,
            float* __restrict__ b768, float* __restrict__ pb,
            __bf16* __restrict__ KVb)
{
    const int bidg = blockIdx.x;
    if (bidg < 216) {
        int idx = bidg * 256 + threadIdx.x;  // 55296
        int lane = idx & 63;
        int rest = idx >> 6;
        int ktg = rest % 18; rest /= 18;
        int qtg = rest & 7;
        int head = rest >> 3;
        int l31 = lane & 31, hi = lane >> 5;
        int q = qtg * 32 + l31;
        bf16x16 o16;
#pragma unroll
        for (int g = 0; g < 4; ++g) {
            int4 ri = *(const int4*)(rpi + q * CNKV + ktg * 32 + 4 * hi + g * 8);
            o16[g * 4 + 0] = (__bf16)(tab[ri.x * CHEADS + head] * LOG2E);
            o16[g * 4 + 1] = (__bf16)(tab[ri.y * CHEADS + head] * LOG2E);
            o16[g * 4 + 2] = (__bf16)(tab[ri.z * CHEADS + head] * LOG2E);
            o16[g * 4 + 3] = (__bf16)(tab[ri.w * CHEADS + head] * LOG2E);
        }
        *(bf16x16*)(BTh + (long)idx * 16) = o16;
    } else if (bidg < 257) {
        int idx = (bidg - 216) * 256 + threadIdx.x;
        if (idx >= 9 * 18 * 64) return;
        int lane = idx & 63;
        int rest = idx >> 6;
        int ktg = rest % 18;
        int cls = rest / 18;
        int cy = cls / 3, cx = cls % 3;
        int hi = lane >> 5;
        u32 m = 0;
#pragma unroll
        for (int r = 0; r < 16; ++r) {
            int kv = ktg * 32 + 4 * hi + (r & 3) + 8 * (r >> 2);
            int oy = kv / 24, ox = kv - oy * 24;
            bool vy = (cy == 0) ? (oy >= 4) : ((cy == 2) ? (oy < 20) : true);
            bool vx = (cx == 0) ? (ox >= 4) : ((cx == 2) ? (ox < 20) : true);
            if (vy && vx) m |= (1u << r);
        }
        mt[idx] = m;
    } else if (bidg < 981) {
        int idx = (bidg - 257) * 256 + threadIdx.x;
        if (idx < 147456) {
            int n = idx / 192, k = idx - n * 192;
            float v;
            if (n < 192)      v = q_w[k * 192 + n] * QSCALE_L2E;
            else if (n < 384) v = g_w[k * 192 + (n - 192)];
            else              v = kv_w[k * 384 + (n - 384)];
            Wt[idx] = (__bf16)v;
        } else if (idx < 184320) {
            int j = idx - 147456;
            int n = j / 192, k = j - n * 192;
            Wp[j] = (__bf16)p_w[k * 192 + n];
        } else if (idx < 185280) {
            int j = idx - 184320;
            if (j < 192)      b768[j] = q_b[j] * QSCALE_L2E;
            else if (j < 384) b768[j] = g_b[j - 192];
            else if (j < 768) b768[j] = kv_b[j - 384];
            else              pb[j - 768] = p_b[j - 768];
        }
    } else {
        int tid = (bidg - 981) * 256 + threadIdx.x;  // 5248 rows * 48 segs
        if (tid >= 251904) return;
        int row = tid / 48, seg = tid - row * 48;
        int bb = row / 2624, rr = row - bb * 2624;
        int py, px;
        if (rr < 672)       { py = rr / 168;               px = rr % 168; }
        else if (rr < 1344) { int r2 = rr - 672; py = 164 + r2 / 168; px = r2 % 168; }
        else                { int rm = rr - 1344; py = 4 + rm / 8; int q = rm & 7;
                              px = (q < 4) ? q : 160 + q; }
        bf16x8 v;
#pragma unroll
        for (int j = 0; j < 8; ++j) v[j] = (__bf16)kv_b[seg * 8 + j];
        *(bf16x8*)(KVb + ((long)((bb * CPH + py) * CPH + px)) * 384 + seg * 8) = v;
    }
}

// ---------------------------------------------------------------------------
// Fused QGKV GEMM v3: SINGLE-STAGE K=192. Whole A[64][192] + B[64][192]
// staged once (XOR-swizzled group-of-8, coalesced 64-col-band loads), ONE
// barrier, then 24 MFMA16s straight. Epilogue unchanged (LDS transpose ->
// coalesced stores). 9600 blocks, XCD-swizzled.
// ---------------------------------------------------------------------------
__global__ __launch_bounds__(256)
void gemm_f_k(const float* __restrict__ x, const __bf16* __restrict__ Wt,
              const float* __restrict__ b768,
              __bf16* __restrict__ Qb, __bf16* __restrict__ Gb,
              __bf16* __restrict__ KVb)
{
    __shared__ __bf16 As[64 * 192];
    __shared__ __bf16 Bs[64 * 192];

    const int bid = blockIdx.x;                 // 9600 = 8 * 1200
    const int v = (bid & 7) * 1200 + (bid >> 3);
    const int bm = v / 12, bn = v - bm * 12;

    const int t = threadIdx.x, lane = t & 63, wv = t >> 6;
    const int l15 = lane & 15, l4 = lane >> 4;
    const int row = t >> 2, gp = t & 3;
    const int swz = row & 7;

    // ---- stage A (f32 -> bf16) and B, fully, once ----
    {
        const float*  asrc = x  + (long)(bm * 64 + row) * 192;
        const __bf16* bsrc = Wt + (long)(bn * 64 + row) * 192;
#pragma unroll
        for (int c = 0; c < 3; ++c) {
            const int col = c * 64 + gp * 16;
            float4 q0 = ((const float4*)(asrc + col))[0];
            float4 q1 = ((const float4*)(asrc + col))[1];
            float4 q2 = ((const float4*)(asrc + col))[2];
            float4 q3 = ((const float4*)(asrc + col))[3];
            bf16x8 g0, g1;
            g0[0] = (__bf16)q0.x; g0[1] = (__bf16)q0.y; g0[2] = (__bf16)q0.z; g0[3] = (__bf16)q0.w;
            g0[4] = (__bf16)q1.x; g0[5] = (__bf16)q1.y; g0[6] = (__bf16)q1.z; g0[7] = (__bf16)q1.w;
            g1[0] = (__bf16)q2.x; g1[1] = (__bf16)q2.y; g1[2] = (__bf16)q2.z; g1[3] = (__bf16)q2.w;
            g1[4] = (__bf16)q3.x; g1[5] = (__bf16)q3.y; g1[6] = (__bf16)q3.z; g1[7] = (__bf16)q3.w;
            const int grp = c * 8 + gp * 2;
            *(bf16x8*)&As[row * 192 + (grp ^ swz) * 8] = g0;
            *(bf16x8*)&As[row * 192 + ((grp + 1) ^ swz) * 8] = g1;
            bf16x8 w0 = *(const bf16x8*)(bsrc + col);
            bf16x8 w1 = *(const bf16x8*)(bsrc + col + 8);
            *(bf16x8*)&Bs[row * 192 + (grp ^ swz) * 8] = w0;
            *(bf16x8*)&Bs[row * 192 + ((grp + 1) ^ swz) * 8] = w1;
        }
    }
    __syncthreads();

    const int qm = (wv >> 1) * 32, qn = (wv & 1) * 32;
    f32x4 acc[2][2];
#pragma unroll
    for (int i = 0; i < 2; ++i)
#pragma unroll
        for (int j = 0; j < 2; ++j) acc[i][j] = f32x4{0.f, 0.f, 0.f, 0.f};

#pragma unroll
    for (int step = 0; step < 6; ++step) {
        bf16x8 af[2], bfr[2];
#pragma unroll
        for (int mi = 0; mi < 2; ++mi)
            af[mi] = *(const bf16x8*)&As[(qm + mi * 16 + l15) * 192 +
                                        (((step * 4 + l4) ^ (l15 & 7)) * 8)];
#pragma unroll
        for (int ni = 0; ni < 2; ++ni)
            bfr[ni] = *(const bf16x8*)&Bs[(qn + ni * 16 + l15) * 192 +
                                          (((step * 4 + l4) ^ (l15 & 7)) * 8)];
#pragma unroll
        for (int mi = 0; mi < 2; ++mi)
#pragma unroll
            for (int ni = 0; ni < 2; ++ni)
                acc[mi][ni] = MFMA16(af[mi], bfr[ni], acc[mi][ni]);
    }
    __syncthreads();

    // ---- epilogue via LDS transpose (reuse As; [64][80] bf16) ----
    __bf16* epi = &As[0];
    float bv0 = b768[bn * 64 + qn + l15];
    float bv1 = b768[bn * 64 + qn + 16 + l15];
#pragma unroll
    for (int mi = 0; mi < 2; ++mi)
#pragma unroll
        for (int ni = 0; ni < 2; ++ni)
#pragma unroll
            for (int r = 0; r < 4; ++r) {
                int rowl = qm + mi * 16 + l4 * 4 + r;
                int coll = qn + ni * 16 + l15;
                epi[rowl * 80 + coll] =
                    (__bf16)(acc[mi][ni][r] + (ni ? bv1 : bv0));
            }
    __syncthreads();
#pragma unroll
    for (int k = 0; k < 2; ++k) {
        int rid = t * 2 + k;
        int rowl = rid >> 3, seg = rid & 7;
        bf16x8 vv = *(const bf16x8*)&epi[rowl * 80 + seg * 8];
        int rowg = bm * 64 + rowl;
        int bb = rowg / 25600, rr = rowg - bb * 25600;
        int y = rr / 160, xx = rr - y * 160;
        int cg = bn * 64 + seg * 8;
        if (bn < 6) {
            int win = bb * 100 + (y >> 4) * 10 + (xx >> 4);
            long widx = ((long)win * 256 + (y & 15) * 16 + (xx & 15)) * 192;
            if (bn < 3) *(bf16x8*)(Qb + widx + cg) = vv;
            else        *(bf16x8*)(Gb + widx + cg - 192) = vv;
        } else {
            long kidx = ((long)((bb * CPH + y + 4) * CPH + (xx + 4))) * 384;
            *(bf16x8*)(KVb + kidx + cg - 384) = vv;
        }
    }
}

// ---------------------------------------------------------------------------
// Projection GEMM v2: SINGLE-STAGE K=192, same scheme (A is already bf16).
// ---------------------------------------------------------------------------
__global__ __launch_bounds__(256)
void gemm_p_k(const __bf16* __restrict__ Yb, const __bf16* __restrict__ Wp,
              const float* __restrict__ pb, float* __restrict__ of)
{
    __shared__ __bf16 As[64 * 192];
    __shared__ __bf16 Bs[64 * 192];

    const int bid = blockIdx.x;                 // 2400 = 8 * 300
    const int v = (bid & 7) * 300 + (bid >> 3);
    const int bm = v / 3, bn = v - bm * 3;

    const int t = threadIdx.x, lane = t & 63, wv = t >> 6;
    const int l15 = lane & 15, l4 = lane >> 4;
    const int row = t >> 2, gp = t & 3;
    const int swz = row & 7;

    {
        const __bf16* asrc = Yb + (long)(bm * 64 + row) * 192;
        const __bf16* bsrc = Wp + (long)(bn * 64 + row) * 192;
#pragma unroll
        for (int c = 0; c < 3; ++c) {
            const int col = c * 64 + gp * 16;
            const int grp = c * 8 + gp * 2;
            bf16x8 a0 = *(const bf16x8*)(asrc + col);
            bf16x8 a1 = *(const bf16x8*)(asrc + col + 8);
            *(bf16x8*)&As[row * 192 + (grp ^ swz) * 8] = a0;
            *(bf16x8*)&As[row * 192 + ((grp + 1) ^ swz) * 8] = a1;
            bf16x8 w0 = *(const bf16x8*)(bsrc + col);
            bf16x8 w1 = *(const bf16x8*)(bsrc + col + 8);
            *(bf16x8*)&Bs[row * 192 + (grp ^ swz) * 8] = w0;
            *(bf16x8*)&Bs[row * 192 + ((grp + 1) ^ swz) * 8] = w1;
        }
    }
    __syncthreads();

    const int qm = (wv >> 1) * 32, qn = (wv & 1) * 32;
    f32x4 acc[2][2];
#pragma unroll
    for (int i = 0; i < 2; ++i)
#pragma unroll
        for (int j = 0; j < 2; ++j) acc[i][j] = f32x4{0.f, 0.f, 0.f, 0.f};

#pragma unroll
    for (int step = 0; step < 6; ++step) {
        bf16x8 af[2], bfr[2];
#pragma unroll
        for (int mi = 0; mi < 2; ++mi)
            af[mi] = *(const bf16x8*)&As[(qm + mi * 16 + l15) * 192 +
                                        (((step * 4 + l4) ^ (l15 & 7)) * 8)];
#pragma unroll
        for (int ni = 0; ni < 2; ++ni)
            bfr[ni] = *(const bf16x8*)&Bs[(qn + ni * 16 + l15) * 192 +
                                          (((step * 4 + l4) ^ (l15 & 7)) * 8)];
#pragma unroll
        for (int mi = 0; mi < 2; ++mi)
#pragma unroll
            for (int ni = 0; ni < 2; ++ni)
                acc[mi][ni] = MFMA16(af[mi], bfr[ni], acc[mi][ni]);
    }

#pragma unroll
    for (int mi = 0; mi < 2; ++mi) {
#pragma unroll
        for (int r = 0; r < 4; ++r) {
            int rowg = bm * 64 + qm + mi * 16 + l4 * 4 + r;   // window row
            int win = rowg >> 8, q = rowg & 255;
            int bb = win / 100, wr = win % 100;
            int y = (wr / 10) * 16 + (q >> 4), xx = (wr % 10) * 16 + (q & 15);
            long oidx = ((long)((bb * CH + y) * CW + xx)) * 192;
#pragma unroll
            for (int ni = 0; ni < 2; ++ni) {
                int cg = bn * 64 + qn + ni * 16 + l15;
                of[oidx + cg] = acc[mi][ni][r] + pb[cg];
            }
        }
    }
}

// ---------------------------------------------------------------------------
// Attention v14 (R16 state, best at 84.2 us): R7 free-run structure + raw
// v_exp_f32 + sum-via-MFMA. Unchanged this round.
// ---------------------------------------------------------------------------
__global__ __launch_bounds__(512, 4)
void attn14_k(const __bf16* __restrict__ Q, const __bf16* __restrict__ KV,
              const __bf16* __restrict__ G, const __bf16* __restrict__ BTh,
              const u32* __restrict__ MT, __bf16* __restrict__ Y)
{
    __shared__ __bf16 Ks[576][36];   // 41,472 B
    __shared__ __bf16 Vt[32][580];   // 37,120 B

    const int bid = blockIdx.x;      // 1200 = 8 * 150
    const int xs = bid & 7, ii = bid >> 3;
    const int win = xs * 25 + ii / 6;
    const int head = ii % 6;

    const int bb = win / 100, wr = win % 100, wy = wr / 10, wx = wr % 10;
    const int cy = (wy == 0) ? 0 : ((wy == 9) ? 2 : 1);
    const int cx = (wx == 0) ? 0 : ((wx == 9) ? 2 : 1);
    const int cls = cy * 3 + cx;
    const int t = threadIdx.x, lane = t & 63, wv = t >> 6;
    const int l31 = lane & 31, hi = lane >> 5;

    // ---- stage whole-window K and V^T (one time) ----
    {
        const int pos0 = t >> 3, seg = t & 7;
        int oy = pos0 / 24, ox = pos0 - oy * 24;
        const long rowbase = ((long)((bb * CPH + wy * 16) * CPH + wx * 16)) * 384
                             + head * CD;
        int pos = pos0;
#pragma unroll
        for (int r = 0; r < 9; ++r) {
            const __bf16* p = KV + rowbase + (long)(oy * CPH + ox) * 384;
            if (seg < 4) {
                bf16x8 k8 = *(const bf16x8*)(p + seg * 8);
                *(bf16x8*)&Ks[pos][seg * 8] = k8;
            } else {
                bf16x8 v8 = *(const bf16x8*)(p + 192 + (seg - 4) * 8);
#pragma unroll
                for (int j = 0; j < 8; ++j) Vt[(seg - 4) * 8 + j][pos] = v8[j];
            }
            pos += 64;
            oy += 2; ox += 16;
            if (ox >= 24) { ox -= 24; oy += 1; }
        }
    }

    bf16x8 qf0, qf1;
    {
        const __bf16* qb = Q + ((long)win * CNQ + wv * 32 + l31) * CC + head * CD;
        qf0 = *(const bf16x8*)(qb + hi * 8);
        qf1 = *(const bf16x8*)(qb + 16 + hi * 8);
    }
    const __bf16* btb = BTh + (long)((head * 8 + wv) * 18) * 1024 + (long)lane * 16;
    bf16x8 bA0 = *(const bf16x8*)(btb);
    bf16x8 bA1 = *(const bf16x8*)(btb + 8);

    bf16x8 ones8;
#pragma unroll
    for (int j = 0; j < 8; ++j) ones8[j] = (__bf16)1.0f;

    __syncthreads();   // the ONLY barrier

    f32x16 o = {};
    f32x16 sacc = {};

    const char* kbase = (const char*)&Ks[0][0] + l31 * 72 + hi * 16;
    const char* vbase = (const char*)&Vt[0][0] + l31 * 1160 + hi * 8;

    bf16x8 kc0 = *(const bf16x8*)(kbase);
    bf16x8 kc1 = *(const bf16x8*)(kbase + 32);

    for (int tt = 0; tt < 18; ++tt) {
        bf16x8 kn0, kn1, bB0, bB1;
        if (tt < 17) {
            const char* kn = kbase + (tt + 1) * 2304;
            kn0 = *(const bf16x8*)(kn);
            kn1 = *(const bf16x8*)(kn + 32);
            bB0 = *(const bf16x8*)(btb + (long)(tt + 1) * 1024);
            bB1 = *(const bf16x8*)(btb + (long)(tt + 1) * 1024 + 8);
        }

        const char* vp = vbase + tt * 64;
        bf16x4 v0 = *(const bf16x4*)(vp);
        bf16x4 v1 = *(const bf16x4*)(vp + 16);
        bf16x4 v2 = *(const bf16x4*)(vp + 32);
        bf16x4 v3 = *(const bf16x4*)(vp + 48);
        bf16x8 vf0, vf1;
#pragma unroll
        for (int j = 0; j < 4; ++j) {
            vf0[j] = v0[j]; vf0[4 + j] = v1[j];
            vf1[j] = v2[j]; vf1[4 + j] = v3[j];
        }

        f32x16 stv;
#pragma unroll
        for (int r = 0; r < 8; ++r) stv[r] = (float)bA0[r];
#pragma unroll
        for (int r = 0; r < 8; ++r) stv[8 + r] = (float)bA1[r];
        __builtin_amdgcn_s_setprio(1);
        stv = MFMA32(kc0, qf0, stv);
        stv = MFMA32(kc1, qf1, stv);
        __builtin_amdgcn_s_setprio(0);

        const bool needm = (cx != 1) || (cy == 0 && tt < 3) || (cy == 2 && tt >= 15);
        u32 m = 0xFFFFFFFFu;
        if (needm) m = MT[(cls * 18 + tt) * 64 + lane];

        float p[16];
#pragma unroll
        for (int r = 0; r < 16; ++r) p[r] = EXP2F(stv[r]);
        if (needm) {
#pragma unroll
            for (int r = 0; r < 16; ++r)
                p[r] = (m & (1u << r)) ? p[r] : 0.0f;
        }

        bf16x8 pa0, pa1;
#pragma unroll
        for (int j = 0; j < 8; ++j) {
            pa0[j] = (__bf16)p[j];
            pa1[j] = (__bf16)p[8 + j];
        }

        __builtin_amdgcn_s_setprio(1);
        o = MFMA32(vf0, pa0, o);
        o = MFMA32(vf1, pa1, o);
        sacc = MFMA32(ones8, pa0, sacc);
        sacc = MFMA32(ones8, pa1, sacc);
        __builtin_amdgcn_s_setprio(0);

        if (tt < 17) {
            kc0 = kn0; kc1 = kn1; bA0 = bB0; bA1 = bB1;
        }
    }

    // ---- epilogue: normalize (sacc fully reduced), gate, store ----
    float rs = 1.0f / sacc[0];
    long base = ((long)win * CNQ + wv * 32 + l31) * CC + head * CD;
    const __bf16* gp2 = G + base;
    __bf16* yp = Y + base;
#pragma unroll
    for (int g = 0; g < 4; ++g) {
        bf16x4 gv = *(const bf16x4*)(gp2 + g * 8 + 4 * hi);
        bf16x4 ov;
#pragma unroll
        for (int j = 0; j < 4; ++j)
            ov[j] = (__bf16)(o[g * 4 + j] * rs * (float)gv[j]);
        *(bf16x4*)(yp + g * 8 + 4 * hi) = ov;
    }
}

// ---------------------------------------------------------------------------
extern "C" void kernel_launch(void* const* d_in, const int* in_sizes, int n_in,
                              void* d_out, int out_size, void* d_ws, size_t ws_size,
                              hipStream_t stream)
{
    (void)in_sizes; (void)n_in; (void)out_size; (void)ws_size;
    const float* x    = (const float*)d_in[0];
    const int*   rpi  = (const int*)  d_in[1];
    // d_in[2] = attn_mask (recomputed analytically)
    const float* q_w  = (const float*)d_in[3];
    const float* q_b  = (const float*)d_in[4];
    const float* kv_w = (const float*)d_in[5];
    const float* kv_b = (const float*)d_in[6];
    const float* btab = (const float*)d_in[7];
    const float* g_w  = (const float*)d_in[8];
    const float* g_b  = (const float*)d_in[9];
    const float* p_w  = (const float*)d_in[10];
    const float* p_b  = (const float*)d_in[11];
    float* out = (float*)d_out;

    char* ws = (char*)d_ws;
    __bf16* Qb  = (__bf16*)(ws);                  // 19,660,800
    __bf16* KVb = (__bf16*)(ws + 19660800);       // 43,352,064
    __bf16* Gb  = (__bf16*)(ws + 63012864);       // 19,660,800
    __bf16* Yb  = (__bf16*)(ws + 82673664);       // 19,660,800
    __bf16* BTh = (__bf16*)(ws + 102334464);      // 1,769,472
    u32*    MT  = (u32*)   (ws + 104103936);      // 41,472
    __bf16* Wt  = (__bf16*)(ws + 104145408);      // 294,912
    __bf16* Wp  = (__bf16*)(ws + 104440320);      // 73,728
    float*  b768= (float*) (ws + 104514048);      // 3,072
    float*  pb  = (float*) (ws + 104517120);      // 768

    prep_k<<<1965, 256, 0, stream>>>(rpi, btab, q_w, g_w, kv_w, p_w,
                                     q_b, g_b, kv_b, p_b,
                                     BTh, MT, Wt, Wp, b768, pb, KVb);
    gemm_f_k<<<9600, 256, 0, stream>>>(x, Wt, b768, Qb, Gb, KVb);
    attn14_k<<<1200, 512, 0, stream>>>(Qb, KVb, Gb, BTh, MT, Yb);
    gemm_p_k<<<2400, 256, 0, stream>>>(Yb, Wp, pb, out);
}

// Round 18
// 139.451 us; speedup vs baseline: 1.0158x; 1.0158x over previous
//
#include <hip/hip_runtime.h>
#include <hip/hip_bf16.h>
#include <stdint.h>

typedef __bf16 bf16x8  __attribute__((ext_vector_type(8)));
typedef __bf16 bf16x4  __attribute__((ext_vector_type(4)));
typedef __bf16 bf16x16 __attribute__((ext_vector_type(16)));
typedef float  f32x4   __attribute__((ext_vector_type(4)));
typedef float  f32x16  __attribute__((ext_vector_type(16)));
typedef uint32_t u32;

#define MFMA16(a, b, c) __builtin_amdgcn_mfma_f32_16x16x32_bf16((a), (b), (c), 0, 0, 0)
#define MFMA32(a, b, c) __builtin_amdgcn_mfma_f32_32x32x16_bf16((a), (b), (c), 0, 0, 0)

#if __has_builtin(__builtin_amdgcn_exp2f)
#define EXP2F(x) __builtin_amdgcn_exp2f(x)
#else
#define EXP2F(x) exp2f(x)
#endif

constexpr int CH = 160, CW = 160, CC = 192, CHEADS = 6, CD = 32;
constexpr int CNQ = 256, CNKV = 576, CPH = 168;
constexpr float LOG2E = 1.44269504088896340736f;
constexpr float QSCALE_L2E = 0.17677669529663687f * 1.44269504088896340736f;

// ---------------------------------------------------------------------------
// Merged prep kernel (R9-proven).
// ---------------------------------------------------------------------------
__global__ __launch_bounds__(256)
void prep_k(const int* __restrict__ rpi, const float* __restrict__ tab,
            const float* __restrict__ q_w, const float* __restrict__ g_w,
            const float* __restrict__ kv_w, const float* __restrict__ p_w,
            const float* __restrict__ q_b, const float* __restrict__ g_b,
            const float* __restrict__ kv_b, const float* __restrict__ p_b,
            __bf16* __restrict__ BTh, u32* __restrict__ mt,
            __bf16* __restrict__ Wt, __bf16* __restrict__ Wp,
            float* __restrict__ b768, float* __restrict__ pb,
            __bf16* __restrict__ KVb)
{
    const int bidg = blockIdx.x;
    if (bidg < 216) {
        int idx = bidg * 256 + threadIdx.x;  // 55296
        int lane = idx & 63;
        int rest = idx >> 6;
        int ktg = rest % 18; rest /= 18;
        int qtg = rest & 7;
        int head = rest >> 3;
        int l31 = lane & 31, hi = lane >> 5;
        int q = qtg * 32 + l31;
        bf16x16 o16;
#pragma unroll
        for (int g = 0; g < 4; ++g) {
            int4 ri = *(const int4*)(rpi + q * CNKV + ktg * 32 + 4 * hi + g * 8);
            o16[g * 4 + 0] = (__bf16)(tab[ri.x * CHEADS + head] * LOG2E);
            o16[g * 4 + 1] = (__bf16)(tab[ri.y * CHEADS + head] * LOG2E);
            o16[g * 4 + 2] = (__bf16)(tab[ri.z * CHEADS + head] * LOG2E);
            o16[g * 4 + 3] = (__bf16)(tab[ri.w * CHEADS + head] * LOG2E);
        }
        *(bf16x16*)(BTh + (long)idx * 16) = o16;
    } else if (bidg < 257) {
        int idx = (bidg - 216) * 256 + threadIdx.x;
        if (idx >= 9 * 18 * 64) return;
        int lane = idx & 63;
        int rest = idx >> 6;
        int ktg = rest % 18;
        int cls = rest / 18;
        int cy = cls / 3, cx = cls % 3;
        int hi = lane >> 5;
        u32 m = 0;
#pragma unroll
        for (int r = 0; r < 16; ++r) {
            int kv = ktg * 32 + 4 * hi + (r & 3) + 8 * (r >> 2);
            int oy = kv / 24, ox = kv - oy * 24;
            bool vy = (cy == 0) ? (oy >= 4) : ((cy == 2) ? (oy < 20) : true);
            bool vx = (cx == 0) ? (ox >= 4) : ((cx == 2) ? (ox < 20) : true);
            if (vy && vx) m |= (1u << r);
        }
        mt[idx] = m;
    } else if (bidg < 981) {
        int idx = (bidg - 257) * 256 + threadIdx.x;
        if (idx < 147456) {
            int n = idx / 192, k = idx - n * 192;
            float v;
            if (n < 192)      v = q_w[k * 192 + n] * QSCALE_L2E;
            else if (n < 384) v = g_w[k * 192 + (n - 192)];
            else              v = kv_w[k * 384 + (n - 384)];
            Wt[idx] = (__bf16)v;
        } else if (idx < 184320) {
            int j = idx - 147456;
            int n = j / 192, k = j - n * 192;
            Wp[j] = (__bf16)p_w[k * 192 + n];
        } else if (idx < 185280) {
            int j = idx - 184320;
            if (j < 192)      b768[j] = q_b[j] * QSCALE_L2E;
            else if (j < 384) b768[j] = g_b[j - 192];
            else if (j < 768) b768[j] = kv_b[j - 384];
            else              pb[j - 768] = p_b[j - 768];
        }
    } else {
        int tid = (bidg - 981) * 256 + threadIdx.x;  // 5248 rows * 48 segs
        if (tid >= 251904) return;
        int row = tid / 48, seg = tid - row * 48;
        int bb = row / 2624, rr = row - bb * 2624;
        int py, px;
        if (rr < 672)       { py = rr / 168;               px = rr % 168; }
        else if (rr < 1344) { int r2 = rr - 672; py = 164 + r2 / 168; px = r2 % 168; }
        else                { int rm = rr - 1344; py = 4 + rm / 8; int q = rm & 7;
                              px = (q < 4) ? q : 160 + q; }
        bf16x8 v;
#pragma unroll
        for (int j = 0; j < 8; ++j) v[j] = (__bf16)kv_b[seg * 8 + j];
        *(bf16x8*)(KVb + ((long)((bb * CPH + py) * CPH + px)) * 384 + seg * 8) = v;
    }
}

// ---------------------------------------------------------------------------
// Fused QGKV GEMM (R9-proven: BM=BN=BK=64, 9600 blocks, XOR-swizzled LDS,
// double-buffered, LDS-transpose epilogue with coalesced stores).
// ---------------------------------------------------------------------------
__global__ __launch_bounds__(256)
void gemm_f_k(const float* __restrict__ x, const __bf16* __restrict__ Wt,
              const float* __restrict__ b768,
              __bf16* __restrict__ Qb, __bf16* __restrict__ Gb,
              __bf16* __restrict__ KVb)
{
    __shared__ __bf16 As[2][4096];
    __shared__ __bf16 Bs[2][4096];

    const int bid = blockIdx.x;                 // 9600 = 8 * 1200
    const int v = (bid & 7) * 1200 + (bid >> 3);
    const int bm = v / 12, bn = v - bm * 12;

    const int t = threadIdx.x, lane = t & 63, wv = t >> 6;
    const int l15 = lane & 15, l4 = lane >> 4;
    const int row = t >> 2, gp = t & 3;
    const int swz = row & 7;
    const int d0 = row * 64 + ((2 * gp) ^ swz) * 8;
    const int d1 = row * 64 + ((2 * gp + 1) ^ swz) * 8;

    const float*  asrc = x  + (long)(bm * 64 + row) * 192 + gp * 16;
    const __bf16* bsrc = Wt + (long)(bn * 64 + row) * 192 + gp * 16;

    float4 fa0, fa1, fa2, fa3;
    bf16x8 wb0, wb1;
    auto ld = [&](int kt) {
        const float* a = asrc + kt * 64;
        fa0 = ((const float4*)a)[0]; fa1 = ((const float4*)a)[1];
        fa2 = ((const float4*)a)[2]; fa3 = ((const float4*)a)[3];
        wb0 = *(const bf16x8*)(bsrc + kt * 64);
        wb1 = *(const bf16x8*)(bsrc + kt * 64 + 8);
    };
    auto st = [&](int buf) {
        bf16x8 g0, g1;
        g0[0] = (__bf16)fa0.x; g0[1] = (__bf16)fa0.y; g0[2] = (__bf16)fa0.z; g0[3] = (__bf16)fa0.w;
        g0[4] = (__bf16)fa1.x; g0[5] = (__bf16)fa1.y; g0[6] = (__bf16)fa1.z; g0[7] = (__bf16)fa1.w;
        g1[0] = (__bf16)fa2.x; g1[1] = (__bf16)fa2.y; g1[2] = (__bf16)fa2.z; g1[3] = (__bf16)fa2.w;
        g1[4] = (__bf16)fa3.x; g1[5] = (__bf16)fa3.y; g1[6] = (__bf16)fa3.z; g1[7] = (__bf16)fa3.w;
        *(bf16x8*)&As[buf][d0] = g0;
        *(bf16x8*)&As[buf][d1] = g1;
        *(bf16x8*)&Bs[buf][d0] = wb0;
        *(bf16x8*)&Bs[buf][d1] = wb1;
    };

    const int qm = (wv >> 1) * 32, qn = (wv & 1) * 32;
    f32x4 acc[2][2];
#pragma unroll
    for (int i = 0; i < 2; ++i)
#pragma unroll
        for (int j = 0; j < 2; ++j) acc[i][j] = f32x4{0.f, 0.f, 0.f, 0.f};

    ld(0);
    for (int kt = 0; kt < 3; ++kt) {
        const int buf = kt & 1;
        st(buf);
        if (kt < 2) ld(kt + 1);
        __syncthreads();
#pragma unroll
        for (int s = 0; s < 2; ++s) {
            bf16x8 af[2], bfr[2];
#pragma unroll
            for (int mi = 0; mi < 2; ++mi)
                af[mi] = *(const bf16x8*)&As[buf][(qm + mi * 16 + l15) * 64 +
                                                 (((s * 4 + l4) ^ (l15 & 7)) * 8)];
#pragma unroll
            for (int ni = 0; ni < 2; ++ni)
                bfr[ni] = *(const bf16x8*)&Bs[buf][(qn + ni * 16 + l15) * 64 +
                                                   (((s * 4 + l4) ^ (l15 & 7)) * 8)];
#pragma unroll
            for (int mi = 0; mi < 2; ++mi)
#pragma unroll
                for (int ni = 0; ni < 2; ++ni)
                    acc[mi][ni] = MFMA16(af[mi], bfr[ni], acc[mi][ni]);
        }
        __syncthreads();
    }

    // ---- epilogue via LDS transpose (reuse As; [64][80] bf16, conflict-free) ----
    __bf16* epi = &As[0][0];
    float bv0 = b768[bn * 64 + qn + l15];
    float bv1 = b768[bn * 64 + qn + 16 + l15];
#pragma unroll
    for (int mi = 0; mi < 2; ++mi)
#pragma unroll
        for (int ni = 0; ni < 2; ++ni)
#pragma unroll
            for (int r = 0; r < 4; ++r) {
                int rowl = qm + mi * 16 + l4 * 4 + r;
                int coll = qn + ni * 16 + l15;
                epi[rowl * 80 + coll] =
                    (__bf16)(acc[mi][ni][r] + (ni ? bv1 : bv0));
            }
    __syncthreads();
#pragma unroll
    for (int k = 0; k < 2; ++k) {
        int rid = t * 2 + k;
        int rowl = rid >> 3, seg = rid & 7;
        bf16x8 vv = *(const bf16x8*)&epi[rowl * 80 + seg * 8];
        int rowg = bm * 64 + rowl;
        int bb = rowg / 25600, rr = rowg - bb * 25600;
        int y = rr / 160, xx = rr - y * 160;
        int cg = bn * 64 + seg * 8;
        if (bn < 6) {
            int win = bb * 100 + (y >> 4) * 10 + (xx >> 4);
            long widx = ((long)win * 256 + (y & 15) * 16 + (xx & 15)) * 192;
            if (bn < 3) *(bf16x8*)(Qb + widx + cg) = vv;
            else        *(bf16x8*)(Gb + widx + cg - 192) = vv;
        } else {
            long kidx = ((long)((bb * CPH + y + 4) * CPH + (xx + 4))) * 384;
            *(bf16x8*)(KVb + kidx + cg - 384) = vv;
        }
    }
}

// ---------------------------------------------------------------------------
// Projection GEMM (R9-proven).
// ---------------------------------------------------------------------------
__global__ __launch_bounds__(256)
void gemm_p_k(const __bf16* __restrict__ Yb, const __bf16* __restrict__ Wp,
              const float* __restrict__ pb, float* __restrict__ of)
{
    __shared__ __bf16 As[2][4096];
    __shared__ __bf16 Bs[2][4096];

    const int bid = blockIdx.x;                 // 2400 = 8 * 300
    const int v = (bid & 7) * 300 + (bid >> 3);
    const int bm = v / 3, bn = v - bm * 3;

    const int t = threadIdx.x, lane = t & 63, wv = t >> 6;
    const int l15 = lane & 15, l4 = lane >> 4;
    const int row = t >> 2, gp = t & 3;
    const int swz = row & 7;
    const int d0 = row * 64 + ((2 * gp) ^ swz) * 8;
    const int d1 = row * 64 + ((2 * gp + 1) ^ swz) * 8;

    const __bf16* asrc = Yb + (long)(bm * 64 + row) * 192 + gp * 16;
    const __bf16* bsrc = Wp + (long)(bn * 64 + row) * 192 + gp * 16;

    bf16x8 a0, a1, wb0, wb1;
    auto ld = [&](int kt) {
        a0  = *(const bf16x8*)(asrc + kt * 64);
        a1  = *(const bf16x8*)(asrc + kt * 64 + 8);
        wb0 = *(const bf16x8*)(bsrc + kt * 64);
        wb1 = *(const bf16x8*)(bsrc + kt * 64 + 8);
    };
    auto st = [&](int buf) {
        *(bf16x8*)&As[buf][d0] = a0;
        *(bf16x8*)&As[buf][d1] = a1;
        *(bf16x8*)&Bs[buf][d0] = wb0;
        *(bf16x8*)&Bs[buf][d1] = wb1;
    };

    const int qm = (wv >> 1) * 32, qn = (wv & 1) * 32;
    f32x4 acc[2][2];
#pragma unroll
    for (int i = 0; i < 2; ++i)
#pragma unroll
        for (int j = 0; j < 2; ++j) acc[i][j] = f32x4{0.f, 0.f, 0.f, 0.f};

    ld(0);
    for (int kt = 0; kt < 3; ++kt) {
        const int buf = kt & 1;
        st(buf);
        if (kt < 2) ld(kt + 1);
        __syncthreads();
#pragma unroll
        for (int s = 0; s < 2; ++s) {
            bf16x8 af[2], bfr[2];
#pragma unroll
            for (int mi = 0; mi < 2; ++mi)
                af[mi] = *(const bf16x8*)&As[buf][(qm + mi * 16 + l15) * 64 +
                                                 (((s * 4 + l4) ^ (l15 & 7)) * 8)];
#pragma unroll
            for (int ni = 0; ni < 2; ++ni)
                bfr[ni] = *(const bf16x8*)&Bs[buf][(qn + ni * 16 + l15) * 64 +
                                                   (((s * 4 + l4) ^ (l15 & 7)) * 8)];
#pragma unroll
            for (int mi = 0; mi < 2; ++mi)
#pragma unroll
                for (int ni = 0; ni < 2; ++ni)
                    acc[mi][ni] = MFMA16(af[mi], bfr[ni], acc[mi][ni]);
        }
        __syncthreads();
    }

#pragma unroll
    for (int mi = 0; mi < 2; ++mi) {
#pragma unroll
        for (int r = 0; r < 4; ++r) {
            int rowg = bm * 64 + qm + mi * 16 + l4 * 4 + r;   // window row
            int win = rowg >> 8, q = rowg & 255;
            int bb = win / 100, wr = win % 100;
            int y = (wr / 10) * 16 + (q >> 4), xx = (wr % 10) * 16 + (q & 15);
            long oidx = ((long)((bb * CH + y) * CW + xx)) * 192;
#pragma unroll
            for (int ni = 0; ni < 2; ++ni) {
                int cg = bn * 64 + qn + ni * 16 + l15;
                of[oidx + cg] = acc[mi][ni][r] + pb[cg];
            }
        }
    }
}

// ---------------------------------------------------------------------------
// Attention v13 (R15 best-measured state): R7 free-run structure + raw
// v_exp_f32 + sum-via-MFMA (sacc fully reduced over K -> no cross-half shfl).
// ---------------------------------------------------------------------------
__global__ __launch_bounds__(512, 4)
void attn13_k(const __bf16* __restrict__ Q, const __bf16* __restrict__ KV,
              const __bf16* __restrict__ G, const __bf16* __restrict__ BTh,
              const u32* __restrict__ MT, __bf16* __restrict__ Y)
{
    __shared__ __bf16 Ks[576][36];   // 41,472 B
    __shared__ __bf16 Vt[32][580];   // 37,120 B

    const int bid = blockIdx.x;      // 1200 = 8 * 150
    const int xs = bid & 7, ii = bid >> 3;
    const int win = xs * 25 + ii / 6;
    const int head = ii % 6;

    const int bb = win / 100, wr = win % 100, wy = wr / 10, wx = wr % 10;
    const int cy = (wy == 0) ? 0 : ((wy == 9) ? 2 : 1);
    const int cx = (wx == 0) ? 0 : ((wx == 9) ? 2 : 1);
    const int cls = cy * 3 + cx;
    const int t = threadIdx.x, lane = t & 63, wv = t >> 6;
    const int l31 = lane & 31, hi = lane >> 5;

    // ---- stage whole-window K and V^T (one time) ----
    {
        const int pos0 = t >> 3, seg = t & 7;
        int oy = pos0 / 24, ox = pos0 - oy * 24;
        const long rowbase = ((long)((bb * CPH + wy * 16) * CPH + wx * 16)) * 384
                             + head * CD;
        int pos = pos0;
#pragma unroll
        for (int r = 0; r < 9; ++r) {
            const __bf16* p = KV + rowbase + (long)(oy * CPH + ox) * 384;
            if (seg < 4) {
                bf16x8 k8 = *(const bf16x8*)(p + seg * 8);
                *(bf16x8*)&Ks[pos][seg * 8] = k8;
            } else {
                bf16x8 v8 = *(const bf16x8*)(p + 192 + (seg - 4) * 8);
#pragma unroll
                for (int j = 0; j < 8; ++j) Vt[(seg - 4) * 8 + j][pos] = v8[j];
            }
            pos += 64;
            oy += 2; ox += 16;
            if (ox >= 24) { ox -= 24; oy += 1; }
        }
    }

    bf16x8 qf0, qf1;
    {
        const __bf16* qb = Q + ((long)win * CNQ + wv * 32 + l31) * CC + head * CD;
        qf0 = *(const bf16x8*)(qb + hi * 8);
        qf1 = *(const bf16x8*)(qb + 16 + hi * 8);
    }
    const __bf16* btb = BTh + (long)((head * 8 + wv) * 18) * 1024 + (long)lane * 16;
    bf16x16 bA = *(const bf16x16*)btb;

    bf16x8 ones8;
#pragma unroll
    for (int j = 0; j < 8; ++j) ones8[j] = (__bf16)1.0f;

    __syncthreads();   // the ONLY barrier

    f32x16 o = {};
    f32x16 sacc = {};

    const char* kbase = (const char*)&Ks[0][0] + l31 * 72 + hi * 16;
    const char* vbase = (const char*)&Vt[0][0] + l31 * 1160 + hi * 8;

    bf16x8 kc0 = *(const bf16x8*)(kbase);
    bf16x8 kc1 = *(const bf16x8*)(kbase + 32);

    for (int tt = 0; tt < 18; ++tt) {
        // prefetch next tile's K frags (LDS) + bias (L2)
        bf16x8 kn0, kn1;
        bf16x16 bB;
        if (tt < 17) {
            const char* kn = kbase + (tt + 1) * 2304;
            kn0 = *(const bf16x8*)(kn);
            kn1 = *(const bf16x8*)(kn + 32);
            bB  = *(const bf16x16*)(btb + (long)(tt + 1) * 1024);
        }

        // V fragments for this tile (conflict-free b64 reads)
        const char* vp = vbase + tt * 64;
        bf16x4 v0 = *(const bf16x4*)(vp);
        bf16x4 v1 = *(const bf16x4*)(vp + 16);
        bf16x4 v2 = *(const bf16x4*)(vp + 32);
        bf16x4 v3 = *(const bf16x4*)(vp + 48);
        bf16x8 vf0, vf1;
#pragma unroll
        for (int j = 0; j < 4; ++j) {
            vf0[j] = v0[j]; vf0[4 + j] = v1[j];
            vf1[j] = v2[j]; vf1[4 + j] = v3[j];
        }

        // scores = bias + K^T Q
        f32x16 stv;
#pragma unroll
        for (int r = 0; r < 16; ++r) stv[r] = (float)bA[r];
        __builtin_amdgcn_s_setprio(1);
        stv = MFMA32(kc0, qf0, stv);
        stv = MFMA32(kc1, qf1, stv);
        __builtin_amdgcn_s_setprio(0);

        const bool needm = (cx != 1) || (cy == 0 && tt < 3) || (cy == 2 && tt >= 15);
        u32 m = 0xFFFFFFFFu;
        if (needm) m = MT[(cls * 18 + tt) * 64 + lane];

        float p[16];
#pragma unroll
        for (int r = 0; r < 16; ++r) p[r] = EXP2F(stv[r]);
        if (needm) {
#pragma unroll
            for (int r = 0; r < 16; ++r)
                p[r] = (m & (1u << r)) ? p[r] : 0.0f;
        }

        bf16x8 pa0, pa1;
#pragma unroll
        for (int j = 0; j < 8; ++j) {
            pa0[j] = (__bf16)p[j];
            pa1[j] = (__bf16)p[8 + j];
        }

        __builtin_amdgcn_s_setprio(1);
        o = MFMA32(vf0, pa0, o);
        o = MFMA32(vf1, pa1, o);
        sacc = MFMA32(ones8, pa0, sacc);
        sacc = MFMA32(ones8, pa1, sacc);
        __builtin_amdgcn_s_setprio(0);

        kc0 = kn0; kc1 = kn1; bA = bB;
    }

    // ---- epilogue: normalize (sacc fully reduced), gate, store ----
    float rs = 1.0f / sacc[0];
    long base = ((long)win * CNQ + wv * 32 + l31) * CC + head * CD;
    const __bf16* gp2 = G + base;
    __bf16* yp = Y + base;
#pragma unroll
    for (int g = 0; g < 4; ++g) {
        bf16x4 gv = *(const bf16x4*)(gp2 + g * 8 + 4 * hi);
        bf16x4 ov;
#pragma unroll
        for (int j = 0; j < 4; ++j)
            ov[j] = (__bf16)(o[g * 4 + j] * rs * (float)gv[j]);
        *(bf16x4*)(yp + g * 8 + 4 * hi) = ov;
    }
}

// ---------------------------------------------------------------------------
extern "C" void kernel_launch(void* const* d_in, const int* in_sizes, int n_in,
                              void* d_out, int out_size, void* d_ws, size_t ws_size,
                              hipStream_t stream)
{
    (void)in_sizes; (void)n_in; (void)out_size; (void)ws_size;
    const float* x    = (const float*)d_in[0];
    const int*   rpi  = (const int*)  d_in[1];
    // d_in[2] = attn_mask (recomputed analytically)
    const float* q_w  = (const float*)d_in[3];
    const float* q_b  = (const float*)d_in[4];
    const float* kv_w = (const float*)d_in[5];
    const float* kv_b = (const float*)d_in[6];
    const float* btab = (const float*)d_in[7];
    const float* g_w  = (const float*)d_in[8];
    const float* g_b  = (const float*)d_in[9];
    const float* p_w  = (const float*)d_in[10];
    const float* p_b  = (const float*)d_in[11];
    float* out = (float*)d_out;

    char* ws = (char*)d_ws;
    __bf16* Qb  = (__bf16*)(ws);                  // 19,660,800
    __bf16* KVb = (__bf16*)(ws + 19660800);       // 43,352,064
    __bf16* Gb  = (__bf16*)(ws + 63012864);       // 19,660,800
    __bf16* Yb  = (__bf16*)(ws + 82673664);       // 19,660,800
    __bf16* BTh = (__bf16*)(ws + 102334464);      // 1,769,472
    u32*    MT  = (u32*)   (ws + 104103936);      // 41,472
    __bf16* Wt  = (__bf16*)(ws + 104145408);      // 294,912
    __bf16* Wp  = (__bf16*)(ws + 104440320);      // 73,728
    float*  b768= (float*) (ws + 104514048);      // 3,072
    float*  pb  = (float*) (ws + 104517120);      // 768

    prep_k<<<1965, 256, 0, stream>>>(rpi, btab, q_w, g_w, kv_w, p_w,
                                     q_b, g_b, kv_b, p_b,
                                     BTh, MT, Wt, Wp, b768, pb, KVb);
    gemm_f_k<<<9600, 256, 0, stream>>>(x, Wt, b768, Qb, Gb, KVb);
    attn13_k<<<1200, 512, 0, stream>>>(Qb, KVb, Gb, BTh, MT, Yb);
    gemm_p_k<<<2400, 256, 0, stream>>>(Yb, Wp, pb, out);
}

// Round 19
// 138.855 us; speedup vs baseline: 1.0202x; 1.0043x over previous
//
#include <hip/hip_runtime.h>
#include <hip/hip_bf16.h>
#include <stdint.h>

typedef __bf16 bf16x8  __attribute__((ext_vector_type(8)));
typedef __bf16 bf16x4  __attribute__((ext_vector_type(4)));
typedef __bf16 bf16x16 __attribute__((ext_vector_type(16)));
typedef float  f32x4   __attribute__((ext_vector_type(4)));
typedef float  f32x16  __attribute__((ext_vector_type(16)));
typedef uint32_t u32;

#define MFMA16(a, b, c) __builtin_amdgcn_mfma_f32_16x16x32_bf16((a), (b), (c), 0, 0, 0)
#define MFMA32(a, b, c) __builtin_amdgcn_mfma_f32_32x32x16_bf16((a), (b), (c), 0, 0, 0)

#if __has_builtin(__builtin_amdgcn_exp2f)
#define EXP2F(x) __builtin_amdgcn_exp2f(x)
#else
#define EXP2F(x) exp2f(x)
#endif

constexpr int CH = 160, CW = 160, CC = 192, CHEADS = 6, CD = 32;
constexpr int CNQ = 256, CNKV = 576, CPH = 168;
constexpr float LOG2E = 1.44269504088896340736f;
constexpr float QSCALE_L2E = 0.17677669529663687f * 1.44269504088896340736f;

// ---------------------------------------------------------------------------
// Merged prep kernel. Bias table now in MFMA *A-operand* layout:
// BTh[((head*8+qtg)*18+ktg)*64 + lane][e], e = h*8+j, holds
//   bias[q = qtg*32 + h*16 + hi*8 + j][kv = ktg*32 + l31] * log2e
// computed ANALYTICALLY: rpi[q][kv] = (39*(oy-qy-7) + (ox-qx-7)) mod 1521.
// ---------------------------------------------------------------------------
__global__ __launch_bounds__(256)
void prep_k(const int* __restrict__ rpi, const float* __restrict__ tab,
            const float* __restrict__ q_w, const float* __restrict__ g_w,
            const float* __restrict__ kv_w, const float* __restrict__ p_w,
            const float* __restrict__ q_b, const float* __restrict__ g_b,
            const float* __restrict__ kv_b, const float* __restrict__ p_b,
            __bf16* __restrict__ BTh, u32* __restrict__ mt,
            __bf16* __restrict__ Wt, __bf16* __restrict__ Wp,
            float* __restrict__ b768, float* __restrict__ pb,
            __bf16* __restrict__ KVb)
{
    (void)rpi;
    const int bidg = blockIdx.x;
    if (bidg < 216) {
        int idx = bidg * 256 + threadIdx.x;  // 55296
        int lane = idx & 63;
        int rest = idx >> 6;
        int ktg = rest % 18; rest /= 18;
        int qtg = rest & 7;
        int head = rest >> 3;
        int l31 = lane & 31, hi = lane >> 5;
        int kv = ktg * 32 + l31;
        int oy = kv / 24, ox = kv - oy * 24;
        bf16x16 o16;
#pragma unroll
        for (int e = 0; e < 16; ++e) {
            int h = e >> 3, j = e & 7;
            int q = qtg * 32 + h * 16 + hi * 8 + j;
            int qy = q >> 4, qx = q & 15;
            int ri = 39 * (oy - qy - 7) + (ox - qx - 7);
            if (ri < 0) ri += 1521;
            o16[e] = (__bf16)(tab[ri * CHEADS + head] * LOG2E);
        }
        *(bf16x16*)(BTh + (long)idx * 16) = o16;
    } else if (bidg < 257) {
        int idx = (bidg - 216) * 256 + threadIdx.x;
        if (idx >= 9 * 18 * 64) return;
        int lane = idx & 63;
        int rest = idx >> 6;
        int ktg = rest % 18;
        int cls = rest / 18;
        int cy = cls / 3, cx = cls % 3;
        int hi = lane >> 5;
        u32 m = 0;
#pragma unroll
        for (int r = 0; r < 16; ++r) {
            int kv = ktg * 32 + 4 * hi + (r & 3) + 8 * (r >> 2);
            int oy = kv / 24, ox = kv - oy * 24;
            bool vy = (cy == 0) ? (oy >= 4) : ((cy == 2) ? (oy < 20) : true);
            bool vx = (cx == 0) ? (ox >= 4) : ((cx == 2) ? (ox < 20) : true);
            if (vy && vx) m |= (1u << r);
        }
        mt[idx] = m;
    } else if (bidg < 981) {
        int idx = (bidg - 257) * 256 + threadIdx.x;
        if (idx < 147456) {
            int n = idx / 192, k = idx - n * 192;
            float v;
            if (n < 192)      v = q_w[k * 192 + n] * QSCALE_L2E;
            else if (n < 384) v = g_w[k * 192 + (n - 192)];
            else              v = kv_w[k * 384 + (n - 384)];
            Wt[idx] = (__bf16)v;
        } else if (idx < 184320) {
            int j = idx - 147456;
            int n = j / 192, k = j - n * 192;
            Wp[j] = (__bf16)p_w[k * 192 + n];
        } else if (idx < 185280) {
            int j = idx - 184320;
            if (j < 192)      b768[j] = q_b[j] * QSCALE_L2E;
            else if (j < 384) b768[j] = g_b[j - 192];
            else if (j < 768) b768[j] = kv_b[j - 384];
            else              pb[j - 768] = p_b[j - 768];
        }
    } else {
        int tid = (bidg - 981) * 256 + threadIdx.x;  // 5248 rows * 48 segs
        if (tid >= 251904) return;
        int row = tid / 48, seg = tid - row * 48;
        int bb = row / 2624, rr = row - bb * 2624;
        int py, px;
        if (rr < 672)       { py = rr / 168;               px = rr % 168; }
        else if (rr < 1344) { int r2 = rr - 672; py = 164 + r2 / 168; px = r2 % 168; }
        else                { int rm = rr - 1344; py = 4 + rm / 8; int q = rm & 7;
                              px = (q < 4) ? q : 160 + q; }
        bf16x8 v;
#pragma unroll
        for (int j = 0; j < 8; ++j) v[j] = (__bf16)kv_b[seg * 8 + j];
        *(bf16x8*)(KVb + ((long)((bb * CPH + py) * CPH + px)) * 384 + seg * 8) = v;
    }
}

// ---------------------------------------------------------------------------
// Fused QGKV GEMM (R9-proven, unchanged).
// ---------------------------------------------------------------------------
__global__ __launch_bounds__(256)
void gemm_f_k(const float* __restrict__ x, const __bf16* __restrict__ Wt,
              const float* __restrict__ b768,
              __bf16* __restrict__ Qb, __bf16* __restrict__ Gb,
              __bf16* __restrict__ KVb)
{
    __shared__ __bf16 As[2][4096];
    __shared__ __bf16 Bs[2][4096];

    const int bid = blockIdx.x;                 // 9600 = 8 * 1200
    const int v = (bid & 7) * 1200 + (bid >> 3);
    const int bm = v / 12, bn = v - bm * 12;

    const int t = threadIdx.x, lane = t & 63, wv = t >> 6;
    const int l15 = lane & 15, l4 = lane >> 4;
    const int row = t >> 2, gp = t & 3;
    const int swz = row & 7;
    const int d0 = row * 64 + ((2 * gp) ^ swz) * 8;
    const int d1 = row * 64 + ((2 * gp + 1) ^ swz) * 8;

    const float*  asrc = x  + (long)(bm * 64 + row) * 192 + gp * 16;
    const __bf16* bsrc = Wt + (long)(bn * 64 + row) * 192 + gp * 16;

    float4 fa0, fa1, fa2, fa3;
    bf16x8 wb0, wb1;
    auto ld = [&](int kt) {
        const float* a = asrc + kt * 64;
        fa0 = ((const float4*)a)[0]; fa1 = ((const float4*)a)[1];
        fa2 = ((const float4*)a)[2]; fa3 = ((const float4*)a)[3];
        wb0 = *(const bf16x8*)(bsrc + kt * 64);
        wb1 = *(const bf16x8*)(bsrc + kt * 64 + 8);
    };
    auto st = [&](int buf) {
        bf16x8 g0, g1;
        g0[0] = (__bf16)fa0.x; g0[1] = (__bf16)fa0.y; g0[2] = (__bf16)fa0.z; g0[3] = (__bf16)fa0.w;
        g0[4] = (__bf16)fa1.x; g0[5] = (__bf16)fa1.y; g0[6] = (__bf16)fa1.z; g0[7] = (__bf16)fa1.w;
        g1[0] = (__bf16)fa2.x; g1[1] = (__bf16)fa2.y; g1[2] = (__bf16)fa2.z; g1[3] = (__bf16)fa2.w;
        g1[4] = (__bf16)fa3.x; g1[5] = (__bf16)fa3.y; g1[6] = (__bf16)fa3.z; g1[7] = (__bf16)fa3.w;
        *(bf16x8*)&As[buf][d0] = g0;
        *(bf16x8*)&As[buf][d1] = g1;
        *(bf16x8*)&Bs[buf][d0] = wb0;
        *(bf16x8*)&Bs[buf][d1] = wb1;
    };

    const int qm = (wv >> 1) * 32, qn = (wv & 1) * 32;
    f32x4 acc[2][2];
#pragma unroll
    for (int i = 0; i < 2; ++i)
#pragma unroll
        for (int j = 0; j < 2; ++j) acc[i][j] = f32x4{0.f, 0.f, 0.f, 0.f};

    ld(0);
    for (int kt = 0; kt < 3; ++kt) {
        const int buf = kt & 1;
        st(buf);
        if (kt < 2) ld(kt + 1);
        __syncthreads();
#pragma unroll
        for (int s = 0; s < 2; ++s) {
            bf16x8 af[2], bfr[2];
#pragma unroll
            for (int mi = 0; mi < 2; ++mi)
                af[mi] = *(const bf16x8*)&As[buf][(qm + mi * 16 + l15) * 64 +
                                                 (((s * 4 + l4) ^ (l15 & 7)) * 8)];
#pragma unroll
            for (int ni = 0; ni < 2; ++ni)
                bfr[ni] = *(const bf16x8*)&Bs[buf][(qn + ni * 16 + l15) * 64 +
                                                   (((s * 4 + l4) ^ (l15 & 7)) * 8)];
#pragma unroll
            for (int mi = 0; mi < 2; ++mi)
#pragma unroll
                for (int ni = 0; ni < 2; ++ni)
                    acc[mi][ni] = MFMA16(af[mi], bfr[ni], acc[mi][ni]);
        }
        __syncthreads();
    }

    // ---- epilogue via LDS transpose ----
    __bf16* epi = &As[0][0];
    float bv0 = b768[bn * 64 + qn + l15];
    float bv1 = b768[bn * 64 + qn + 16 + l15];
#pragma unroll
    for (int mi = 0; mi < 2; ++mi)
#pragma unroll
        for (int ni = 0; ni < 2; ++ni)
#pragma unroll
            for (int r = 0; r < 4; ++r) {
                int rowl = qm + mi * 16 + l4 * 4 + r;
                int coll = qn + ni * 16 + l15;
                epi[rowl * 80 + coll] =
                    (__bf16)(acc[mi][ni][r] + (ni ? bv1 : bv0));
            }
    __syncthreads();
#pragma unroll
    for (int k = 0; k < 2; ++k) {
        int rid = t * 2 + k;
        int rowl = rid >> 3, seg = rid & 7;
        bf16x8 vv = *(const bf16x8*)&epi[rowl * 80 + seg * 8];
        int rowg = bm * 64 + rowl;
        int bb = rowg / 25600, rr = rowg - bb * 25600;
        int y = rr / 160, xx = rr - y * 160;
        int cg = bn * 64 + seg * 8;
        if (bn < 6) {
            int win = bb * 100 + (y >> 4) * 10 + (xx >> 4);
            long widx = ((long)win * 256 + (y & 15) * 16 + (xx & 15)) * 192;
            if (bn < 3) *(bf16x8*)(Qb + widx + cg) = vv;
            else        *(bf16x8*)(Gb + widx + cg - 192) = vv;
        } else {
            long kidx = ((long)((bb * CPH + y + 4) * CPH + (xx + 4))) * 384;
            *(bf16x8*)(KVb + kidx + cg - 384) = vv;
        }
    }
}

// ---------------------------------------------------------------------------
// Projection GEMM (R9-proven, unchanged).
// ---------------------------------------------------------------------------
__global__ __launch_bounds__(256)
void gemm_p_k(const __bf16* __restrict__ Yb, const __bf16* __restrict__ Wp,
              const float* __restrict__ pb, float* __restrict__ of)
{
    __shared__ __bf16 As[2][4096];
    __shared__ __bf16 Bs[2][4096];

    const int bid = blockIdx.x;                 // 2400 = 8 * 300
    const int v = (bid & 7) * 300 + (bid >> 3);
    const int bm = v / 3, bn = v - bm * 3;

    const int t = threadIdx.x, lane = t & 63, wv = t >> 6;
    const int l15 = lane & 15, l4 = lane >> 4;
    const int row = t >> 2, gp = t & 3;
    const int swz = row & 7;
    const int d0 = row * 64 + ((2 * gp) ^ swz) * 8;
    const int d1 = row * 64 + ((2 * gp + 1) ^ swz) * 8;

    const __bf16* asrc = Yb + (long)(bm * 64 + row) * 192 + gp * 16;
    const __bf16* bsrc = Wp + (long)(bn * 64 + row) * 192 + gp * 16;

    bf16x8 a0, a1, wb0, wb1;
    auto ld = [&](int kt) {
        a0  = *(const bf16x8*)(asrc + kt * 64);
        a1  = *(const bf16x8*)(asrc + kt * 64 + 8);
        wb0 = *(const bf16x8*)(bsrc + kt * 64);
        wb1 = *(const bf16x8*)(bsrc + kt * 64 + 8);
    };
    auto st = [&](int buf) {
        *(bf16x8*)&As[buf][d0] = a0;
        *(bf16x8*)&As[buf][d1] = a1;
        *(bf16x8*)&Bs[buf][d0] = wb0;
        *(bf16x8*)&Bs[buf][d1] = wb1;
    };

    const int qm = (wv >> 1) * 32, qn = (wv & 1) * 32;
    f32x4 acc[2][2];
#pragma unroll
    for (int i = 0; i < 2; ++i)
#pragma unroll
        for (int j = 0; j < 2; ++j) acc[i][j] = f32x4{0.f, 0.f, 0.f, 0.f};

    ld(0);
    for (int kt = 0; kt < 3; ++kt) {
        const int buf = kt & 1;
        st(buf);
        if (kt < 2) ld(kt + 1);
        __syncthreads();
#pragma unroll
        for (int s = 0; s < 2; ++s) {
            bf16x8 af[2], bfr[2];
#pragma unroll
            for (int mi = 0; mi < 2; ++mi)
                af[mi] = *(const bf16x8*)&As[buf][(qm + mi * 16 + l15) * 64 +
                                                 (((s * 4 + l4) ^ (l15 & 7)) * 8)];
#pragma unroll
            for (int ni = 0; ni < 2; ++ni)
                bfr[ni] = *(const bf16x8*)&Bs[buf][(qn + ni * 16 + l15) * 64 +
                                                   (((s * 4 + l4) ^ (l15 & 7)) * 8)];
#pragma unroll
            for (int mi = 0; mi < 2; ++mi)
#pragma unroll
                for (int ni = 0; ni < 2; ++ni)
                    acc[mi][ni] = MFMA16(af[mi], bfr[ni], acc[mi][ni]);
        }
        __syncthreads();
    }

#pragma unroll
    for (int mi = 0; mi < 2; ++mi) {
#pragma unroll
        for (int r = 0; r < 4; ++r) {
            int rowg = bm * 64 + qm + mi * 16 + l4 * 4 + r;   // window row
            int win = rowg >> 8, q = rowg & 255;
            int bb = win / 100, wr = win % 100;
            int y = (wr / 10) * 16 + (q >> 4), xx = (wr % 10) * 16 + (q & 15);
            long oidx = ((long)((bb * CH + y) * CW + xx)) * 192;
#pragma unroll
            for (int ni = 0; ni < 2; ++ni) {
                int cg = bn * 64 + qn + ni * 16 + l15;
                of[oidx + cg] = acc[mi][ni][r] + pb[cg];
            }
        }
    }
}

// ---------------------------------------------------------------------------
// Attention v15: R18's attn13 + VALU offload.
// (a) bias applied via 2 identity-B MFMAs (A = bias in A-operand layout) —
//     deletes 16 v_cvt per tile;
// (b) V^T columns pre-permuted (swap bits 2<->3 of kv%32 = the PV slot->kv
//     involution) so V fragments are two aligned ds_read_b128 — deletes 8
//     VALU moves + 2 load issues per tile. Row stride 584 (1168B, 16B-align).
// ---------------------------------------------------------------------------
__global__ __launch_bounds__(512, 4)
void attn15_k(const __bf16* __restrict__ Q, const __bf16* __restrict__ KV,
              const __bf16* __restrict__ G, const __bf16* __restrict__ BTh,
              const u32* __restrict__ MT, __bf16* __restrict__ Y)
{
    __shared__ __bf16 Ks[576][36];   // 41,472 B
    __shared__ __bf16 Vt[32][584];   // 37,376 B (16B-aligned rows)

    const int bid = blockIdx.x;      // 1200 = 8 * 150
    const int xs = bid & 7, ii = bid >> 3;
    const int win = xs * 25 + ii / 6;
    const int head = ii % 6;

    const int bb = win / 100, wr = win % 100, wy = wr / 10, wx = wr % 10;
    const int cy = (wy == 0) ? 0 : ((wy == 9) ? 2 : 1);
    const int cx = (wx == 0) ? 0 : ((wx == 9) ? 2 : 1);
    const int cls = cy * 3 + cx;
    const int t = threadIdx.x, lane = t & 63, wv = t >> 6;
    const int l31 = lane & 31, hi = lane >> 5;

    // ---- stage whole-window K and permuted V^T (one time) ----
    {
        const int pos0 = t >> 3, seg = t & 7;
        int oy = pos0 / 24, ox = pos0 - oy * 24;
        const long rowbase = ((long)((bb * CPH + wy * 16) * CPH + wx * 16)) * 384
                             + head * CD;
        int pos = pos0;
#pragma unroll
        for (int r = 0; r < 9; ++r) {
            const __bf16* p = KV + rowbase + (long)(oy * CPH + ox) * 384;
            if (seg < 4) {
                bf16x8 k8 = *(const bf16x8*)(p + seg * 8);
                *(bf16x8*)&Ks[pos][seg * 8] = k8;
            } else {
                bf16x8 v8 = *(const bf16x8*)(p + 192 + (seg - 4) * 8);
                int w = pos & 31;
                int cp = (pos & ~31) | (w & 19) | ((w & 4) << 1) | ((w & 8) >> 1);
#pragma unroll
                for (int j = 0; j < 8; ++j) Vt[(seg - 4) * 8 + j][cp] = v8[j];
            }
            pos += 64;
            oy += 2; ox += 16;
            if (ox >= 24) { ox -= 24; oy += 1; }
        }
    }

    bf16x8 qf0, qf1;
    {
        const __bf16* qb = Q + ((long)win * CNQ + wv * 32 + l31) * CC + head * CD;
        qf0 = *(const bf16x8*)(qb + hi * 8);
        qf1 = *(const bf16x8*)(qb + 16 + hi * 8);
    }
    const __bf16* btb = BTh + (long)((head * 8 + wv) * 18) * 1024 + (long)lane * 16;
    bf16x8 bA0 = *(const bf16x8*)(btb);
    bf16x8 bA1 = *(const bf16x8*)(btb + 8);

    bf16x8 ones8, I0, I1;
#pragma unroll
    for (int j = 0; j < 8; ++j) {
        ones8[j] = (__bf16)1.0f;
        I0[j] = (__bf16)((l31 == hi * 8 + j) ? 1.0f : 0.0f);
        I1[j] = (__bf16)((l31 == 16 + hi * 8 + j) ? 1.0f : 0.0f);
    }

    __syncthreads();   // the ONLY barrier

    f32x16 o = {};
    f32x16 sacc = {};

    const char* kbase = (const char*)&Ks[0][0] + l31 * 72 + hi * 16;
    const char* vbase = (const char*)&Vt[0][0] + l31 * 1168 + hi * 16;

    bf16x8 kc0 = *(const bf16x8*)(kbase);
    bf16x8 kc1 = *(const bf16x8*)(kbase + 32);

    for (int tt = 0; tt < 18; ++tt) {
        // prefetch next tile's K frags (LDS) + bias (L2)
        bf16x8 kn0, kn1, bB0, bB1;
        if (tt < 17) {
            const char* kn = kbase + (tt + 1) * 2304;
            kn0 = *(const bf16x8*)(kn);
            kn1 = *(const bf16x8*)(kn + 32);
            bB0 = *(const bf16x8*)(btb + (long)(tt + 1) * 1024);
            bB1 = *(const bf16x8*)(btb + (long)(tt + 1) * 1024 + 8);
        }

        // V fragments: two aligned b128 reads (pre-permuted slot order)
        const char* vp = vbase + tt * 64;
        bf16x8 vf0 = *(const bf16x8*)(vp);
        bf16x8 vf1 = *(const bf16x8*)(vp + 32);

        // scores: bias via identity MFMAs, then QK^T
        f32x16 stv = {};
        __builtin_amdgcn_s_setprio(1);
        stv = MFMA32(bA0, I0, stv);
        stv = MFMA32(bA1, I1, stv);
        stv = MFMA32(kc0, qf0, stv);
        stv = MFMA32(kc1, qf1, stv);
        __builtin_amdgcn_s_setprio(0);

        const bool needm = (cx != 1) || (cy == 0 && tt < 3) || (cy == 2 && tt >= 15);
        u32 m = 0xFFFFFFFFu;
        if (needm) m = MT[(cls * 18 + tt) * 64 + lane];

        float p[16];
#pragma unroll
        for (int r = 0; r < 16; ++r) p[r] = EXP2F(stv[r]);
        if (needm) {
#pragma unroll
            for (int r = 0; r < 16; ++r)
                p[r] = (m & (1u << r)) ? p[r] : 0.0f;
        }

        bf16x8 pa0, pa1;
#pragma unroll
        for (int j = 0; j < 8; ++j) {
            pa0[j] = (__bf16)p[j];
            pa1[j] = (__bf16)p[8 + j];
        }

        __builtin_amdgcn_s_setprio(1);
        o = MFMA32(vf0, pa0, o);
        o = MFMA32(vf1, pa1, o);
        sacc = MFMA32(ones8, pa0, sacc);
        sacc = MFMA32(ones8, pa1, sacc);
        __builtin_amdgcn_s_setprio(0);

        if (tt < 17) {
            kc0 = kn0; kc1 = kn1; bA0 = bB0; bA1 = bB1;
        }
    }

    // ---- epilogue: normalize (sacc fully reduced), gate, store ----
    float rs = 1.0f / sacc[0];
    long base = ((long)win * CNQ + wv * 32 + l31) * CC + head * CD;
    const __bf16* gp2 = G + base;
    __bf16* yp = Y + base;
#pragma unroll
    for (int g = 0; g < 4; ++g) {
        bf16x4 gv = *(const bf16x4*)(gp2 + g * 8 + 4 * hi);
        bf16x4 ov;
#pragma unroll
        for (int j = 0; j < 4; ++j)
            ov[j] = (__bf16)(o[g * 4 + j] * rs * (float)gv[j]);
        *(bf16x4*)(yp + g * 8 + 4 * hi) = ov;
    }
}

// ---------------------------------------------------------------------------
extern "C" void kernel_launch(void* const* d_in, const int* in_sizes, int n_in,
                              void* d_out, int out_size, void* d_ws, size_t ws_size,
                              hipStream_t stream)
{
    (void)in_sizes; (void)n_in; (void)out_size; (void)ws_size;
    const float* x    = (const float*)d_in[0];
    const int*   rpi  = (const int*)  d_in[1];
    // d_in[2] = attn_mask (recomputed analytically)
    const float* q_w  = (const float*)d_in[3];
    const float* q_b  = (const float*)d_in[4];
    const float* kv_w = (const float*)d_in[5];
    const float* kv_b = (const float*)d_in[6];
    const float* btab = (const float*)d_in[7];
    const float* g_w  = (const float*)d_in[8];
    const float* g_b  = (const float*)d_in[9];
    const float* p_w  = (const float*)d_in[10];
    const float* p_b  = (const float*)d_in[11];
    float* out = (float*)d_out;

    char* ws = (char*)d_ws;
    __bf16* Qb  = (__bf16*)(ws);                  // 19,660,800
    __bf16* KVb = (__bf16*)(ws + 19660800);       // 43,352,064
    __bf16* Gb  = (__bf16*)(ws + 63012864);       // 19,660,800
    __bf16* Yb  = (__bf16*)(ws + 82673664);       // 19,660,800
    __bf16* BTh = (__bf16*)(ws + 102334464);      // 1,769,472
    u32*    MT  = (u32*)   (ws + 104103936);      // 41,472
    __bf16* Wt  = (__bf16*)(ws + 104145408);      // 294,912
    __bf16* Wp  = (__bf16*)(ws + 104440320);      // 73,728
    float*  b768= (float*) (ws + 104514048);      // 3,072
    float*  pb  = (float*) (ws + 104517120);      // 768

    prep_k<<<1965, 256, 0, stream>>>(rpi, btab, q_w, g_w, kv_w, p_w,
                                     q_b, g_b, kv_b, p_b,
                                     BTh, MT, Wt, Wp, b768, pb, KVb);
    gemm_f_k<<<9600, 256, 0, stream>>>(x, Wt, b768, Qb, Gb, KVb);
    attn15_k<<<1200, 512, 0, stream>>>(Qb, KVb, Gb, BTh, MT, Yb);
    gemm_p_k<<<2400, 256, 0, stream>>>(Yb, Wp, pb, out);
}